// Round 12
// baseline (155.137 us; speedup 1.0000x reference)
//
#include <hip/hip_runtime.h>
#include <stdint.h>

typedef __bf16 bf16;
typedef bf16 bf16x8 __attribute__((ext_vector_type(8)));
typedef bf16 bf16x4 __attribute__((ext_vector_type(4)));
typedef float f32x4 __attribute__((ext_vector_type(4)));
typedef float f32x16 __attribute__((ext_vector_type(16)));
typedef unsigned int uint;
typedef uint u32x4 __attribute__((ext_vector_type(4)));

#define MFMA16(a, b, c) __builtin_amdgcn_mfma_f32_16x16x32_bf16(a, b, c, 0, 0, 0)
#define MFMA32(a, b, c) __builtin_amdgcn_mfma_f32_32x32x16_bf16(a, b, c, 0, 0, 0)

static constexpr int Bsz = 2, T = 2048, E = 1024, H = 16, Dh = 64;
// softmax scale folded into Q at projection; exp2-domain: 1/sqrt(64) * log2(e)
static constexpr float QSCALE = 0.125f * 1.44269504088896f;

__device__ __forceinline__ float exp2fast(float x) {
#if __has_builtin(__builtin_amdgcn_exp2f)
    return __builtin_amdgcn_exp2f(x);
#else
    return exp2f(x);
#endif
}

// async global->LDS, 16B per lane. LDS dest must be wave-uniform base (HW adds lane*16).
__device__ __forceinline__ void gll16(const bf16* g, bf16* l) {
    __builtin_amdgcn_global_load_lds((const __attribute__((address_space(1))) uint*)g,
                                     (__attribute__((address_space(3))) uint*)l, 16, 0, 0);
}

// ---- staging: ROWS x 64 bf16 tile into linear LDS ([row][64], 128B rows) ----
template <int ROWS>
__device__ __forceinline__ void stage_b16(bf16* lds, const bf16* g, int ldg, int wave, int lane) {
#pragma unroll
    for (int i = 0; i < ROWS / 32; ++i) {
        const int row = wave * (ROWS / 4) + i * 8;  // wave-uniform
        gll16(g + (size_t)(row + (lane >> 3)) * ldg + (lane & 7) * 8, lds + row * 64);
    }
}
template <int ROWS>
__device__ __forceinline__ void stage_f32(bf16* lds, const float* g, int ldg, int tid) {
#pragma unroll
    for (int i = 0; i < ROWS / 16; ++i) {
        int gg = tid + i * 256;
        int row = gg >> 4, c4 = (gg & 15) << 2;
        const float4 v = *(const float4*)(g + (size_t)row * ldg + c4);
        bf16x4 bv = {(bf16)v.x, (bf16)v.y, (bf16)v.z, (bf16)v.w};
        *(bf16x4*)(lds + row * 64 + c4) = bv;
    }
}

// ------------- GEMM body: Y[M,N] = A[M,K] @ B[N,K]^T (+bias) ---------------
template <bool AB16, bool BB16, int MF, int NF, bool OUTF32>
__device__ __forceinline__ void gemm_body(bf16* At, bf16* Bt,
                                          const bf16* A16, const float* A32,
                                          const bf16* B16, const float* B32,
                                          bf16* Yb, float* Yf, const float* bias,
                                          int m0, int n0, int K, int ldy, float oscale) {
    constexpr int BM = MF * 32, BN = NF * 32;
    const int tid = threadIdx.x, lane = tid & 63, wave = tid >> 6;
    const int wm = wave >> 1, wn = wave & 1;
    const int fr = lane & 15, kg = (lane >> 4) << 3;

    f32x4 acc[MF][NF] = {};

    for (int k0 = 0; k0 < K; k0 += 64) {
        if constexpr (AB16)
            stage_b16<BM>(At, A16 + (size_t)m0 * K + k0, K, wave, lane);
        else
            stage_f32<BM>(At, A32 + (size_t)m0 * K + k0, K, tid);
        if constexpr (BB16)
            stage_b16<BN>(Bt, B16 + (size_t)n0 * K + k0, K, wave, lane);
        else
            stage_f32<BN>(Bt, B32 + (size_t)n0 * K + k0, K, tid);
        __syncthreads();  // compiler drains vmcnt(0) for global_load_lds here
#pragma unroll
        for (int kk = 0; kk < 64; kk += 32) {
            bf16x8 af[MF], bfr[NF];
#pragma unroll
            for (int f = 0; f < MF; ++f)
                af[f] = *(const bf16x8*)(At + (wm * (BM / 2) + f * 16 + fr) * 64 + kk + kg);
#pragma unroll
            for (int f = 0; f < NF; ++f)
                bfr[f] = *(const bf16x8*)(Bt + (wn * (BN / 2) + f * 16 + fr) * 64 + kk + kg);
#pragma unroll
            for (int mf = 0; mf < MF; ++mf)
#pragma unroll
                for (int nf = 0; nf < NF; ++nf)
                    acc[mf][nf] = MFMA16(af[mf], bfr[nf], acc[mf][nf]);
        }
        __syncthreads();
    }
    const int rb = (lane >> 4) << 2;
#pragma unroll
    for (int mf = 0; mf < MF; ++mf)
#pragma unroll
        for (int nf = 0; nf < NF; ++nf) {
            int n = n0 + wn * (BN / 2) + nf * 16 + fr;
            float bn = 0.f;
            if constexpr (OUTF32) bn = bias[n];
#pragma unroll
            for (int r = 0; r < 4; ++r) {
                int mm = m0 + wm * (BM / 2) + mf * 16 + rb + r;
                float v = acc[mf][nf][r];
                if constexpr (OUTF32)
                    Yf[(size_t)mm * ldy + n] = v + bn;
                else
                    Yb[(size_t)mm * ldy + n] = (bf16)(v * oscale);
            }
        }
}

// fp32 -> bf16 conversion pass (x inputs optional). 16M elems max, 4/thread.
__global__ __launch_bounds__(256) void cvt_all(const float* q, const float* k, const float* v,
                                               const float* Wq, const float* Wk,
                                               const float* Wv, const float* Wo,
                                               bf16* qc, bf16* kc, bf16* vc,
                                               bf16* Wqc, bf16* Wkc, bf16* Wvc, bf16* Woc,
                                               int doX) {
    const size_t NX = (size_t)Bsz * T * E;  // 4M
    const size_t NW = (size_t)E * E;        // 1M
    const size_t xtot = doX ? 3 * NX : 0;
    const size_t nwork = (xtot + 4 * NW) >> 2;
    for (size_t t = (size_t)blockIdx.x * 256 + threadIdx.x; t < nwork;
         t += (size_t)gridDim.x * 256) {
        size_t i = t << 2;
        const float* s;
        bf16* d;
        size_t off;
        if (i < xtot) {
            size_t w = i / NX;
            off = i - w * NX;
            s = w == 0 ? q : (w == 1 ? k : v);
            d = w == 0 ? qc : (w == 1 ? kc : vc);
        } else {
            size_t j = i - xtot;
            size_t w = j / NW;
            off = j - w * NW;
            s = w == 0 ? Wq : (w == 1 ? Wk : (w == 2 ? Wv : Wo));
            d = w == 0 ? Wqc : (w == 1 ? Wkc : (w == 2 ? Wvc : Woc));
        }
        const float4 x = *(const float4*)(s + off);
        bf16x4 y = {(bf16)x.x, (bf16)x.y, (bf16)x.z, (bf16)x.w};
        *(bf16x4*)(d + off) = y;
    }
}

// Fused Q/K/V^T projections: 768 blocks, XCD-swizzled, no dead blocks.
template <bool XB16, bool WB16>
__global__ __launch_bounds__(256) void qkv_proj(
    const float* q32, const float* k32, const float* v32,
    const bf16* q16, const bf16* k16, const bf16* v16,
    const float* Wq32, const float* Wk32, const float* Wv32,
    const bf16* Wq16, const bf16* Wk16, const bf16* Wv16,
    bf16* Qb, bf16* Kb, bf16* Vt) {
    __shared__ bf16 At[128 * 64];
    __shared__ bf16 Bt[128 * 64];
    const int bid = blockIdx.x;
    const int wid = (bid & 7) * 96 + (bid >> 3);  // 768 % 8 == 0: bijective
    if (wid < 512) {
        int s = wid >> 8;  // 0=Q (scaled by QSCALE), 1=K
        int t = wid & 255;
        int m0 = (t >> 3) * 128, n0 = (t & 7) * 128;
        gemm_body<XB16, WB16, 4, 4, false>(At, Bt,
                                           s ? k16 : q16, s ? k32 : q32,
                                           s ? Wk16 : Wq16, s ? Wk32 : Wq32,
                                           s ? Kb : Qb, nullptr, nullptr, m0, n0, E, E,
                                           s ? 1.0f : QSCALE);
    } else {
        int r = wid - 512;
        int b = r >> 7, rr = r & 127;
        int m0 = (rr >> 4) * 128, n0 = (rr & 15) * 128;
        gemm_body<WB16, XB16, 4, 4, false>(At, Bt,
                                           Wv16, Wv32,
                                           v16 + (size_t)b * T * E, v32 + (size_t)b * T * E,
                                           Vt + (size_t)b * E * T, nullptr, nullptr,
                                           m0, n0, E, T, 1.0f);
    }
}

// Output projection: 64x128 tiles -> 512 blocks (2/CU), fp32 out + bias.
template <bool WB16>
__global__ __launch_bounds__(256) void out_proj(const bf16* Xb, const bf16* W16,
                                                const float* W32, float* Y,
                                                const float* bias) {
    __shared__ bf16 At[64 * 64];
    __shared__ bf16 Bt[128 * 64];
    const int bid = blockIdx.x;
    const int wid = (bid & 7) * 64 + (bid >> 3);  // 512 % 8 == 0: bijective
    const int m0 = (wid >> 3) * 64, n0 = (wid & 7) * 128;
    gemm_body<true, WB16, 2, 4, true>(At, Bt, Xb, nullptr, W16, W32, nullptr, Y, bias,
                                      m0, n0, E, E, 1.0f);
}

// ---------------- Attention: flash, shared LDS-staged K/V tiles ------------
__device__ __forceinline__ uint pkbf(float a, float b) {
    uint16_t x = __builtin_bit_cast(uint16_t, (bf16)a);
    uint16_t y = __builtin_bit_cast(uint16_t, (bf16)b);
    return (uint)x | ((uint)y << 16);
}

// Stage one 128-key K/V tile (this wave's share): K[128 rows][64] + V[64][128].
// Linear LDS dest + pre-swizzled global source: LDS[row][c] = global[row][c^(row&7)].
__device__ __forceinline__ void stageKV128(const bf16* Kg, const bf16* Vg,
                                           bf16* dK, bf16* dV, int w, int lane) {
#pragma unroll
    for (int ii = 0; ii < 4; ++ii) {
        const int r0 = 32 * w + 8 * ii;  // K rows, 64-col rows (8 chunks)
        gll16(Kg + (size_t)(r0 + (lane >> 3)) * E + (((lane & 7) ^ (lane >> 3)) << 3),
              dK + r0 * 64);
    }
#pragma unroll
    for (int ii = 0; ii < 4; ++ii) {
        const int r0 = 16 * w + 4 * ii;  // V rows (d), 128-col rows (16 chunks)
        const int fb = (4 * ii) & 7;     // == r0 & 7
        const int csw = (lane & 15) ^ ((fb + (lane >> 4)) & 7);
        gll16(Vg + (size_t)(r0 + (lane >> 4)) * T + (csw << 3), dV + r0 * 128);
    }
}

// One flat 128-key tile. NG = live 32-key groups (1..4); DG = diag-masked
// group (-1 = interior). ONE softmax pass over all live scores.
template <int NG, int DG>
__device__ __forceinline__ void attn_tile128(const bf16* KL, const bf16* VL,
                                             int l31, int hi, int swz,
                                             const bf16x8 (&qf)[4],
                                             f32x16& o0, f32x16& o1, float& m, float& l) {
    f32x16 s[4];  // static-indexed only (unrolled / constexpr)
#pragma unroll
    for (int g = 0; g < NG; ++g) {
        bf16x8 kf[4];
#pragma unroll
        for (int t = 0; t < 4; ++t)
            kf[t] = *(const bf16x8*)(KL + (g * 32 + l31) * 64 + ((((t << 1) | hi) ^ swz) << 3));
        f32x16 acc = {};
        __builtin_amdgcn_s_setprio(1);
#pragma unroll
        for (int t = 0; t < 4; ++t) acc = MFMA32(kf[t], qf[t], acc);
        __builtin_amdgcn_s_setprio(0);
        s[g] = acc;
    }
    // V fragments preloaded: ds_read latency hides under softmax VALU
    bf16x8 vfa[2 * NG], vfb[2 * NG];
#pragma unroll
    for (int cc = 0; cc < 2 * NG; ++cc) {
        vfa[cc] = *(const bf16x8*)(VL + l31 * 128 + ((((cc << 1) | hi) ^ swz) << 3));
        vfb[cc] = *(const bf16x8*)(VL + (32 + l31) * 128 + ((((cc << 1) | hi) ^ swz) << 3));
    }
    // causal mask on the diagonal group
    if constexpr (DG >= 0) {
#pragma unroll
        for (int r = 0; r < 16; ++r) {
            int key = (r & 3) + 8 * (r >> 2) + 4 * hi;
            if (key > l31) s[DG][r] = -1e30f;
        }
    }
    // single row-max tree over all live groups
    float t8[8];
#pragma unroll
    for (int r = 0; r < 8; ++r) {
        float v = fmaxf(s[0][r], s[0][r + 8]);
#pragma unroll
        for (int g = 1; g < NG; ++g) v = fmaxf(v, fmaxf(s[g][r], s[g][r + 8]));
        t8[r] = v;
    }
#pragma unroll
    for (int r = 0; r < 4; ++r) t8[r] = fmaxf(t8[r], t8[r + 4]);
    float pm = fmaxf(fmaxf(t8[0], t8[1]), fmaxf(t8[2], t8[3]));
    pm = fmaxf(pm, __shfl_xor(pm, 32, 64));

    if (!__all(pm - m <= 11.5f)) {  // deferred rescale (T13), 8*log2e
        float mn = fmaxf(m, pm);
        float al = exp2fast(m - mn);
        m = mn;
        l *= al;
#pragma unroll
        for (int r = 0; r < 16; ++r) {
            int qr = (r & 3) + 8 * (r >> 2) + 4 * hi;
            float aq = __shfl(al, qr, 64);
            o0[r] *= aq;
            o1[r] *= aq;
        }
    }
    // exp in place, single sum tree
#pragma unroll
    for (int g = 0; g < NG; ++g)
#pragma unroll
        for (int r = 0; r < 16; ++r) s[g][r] = exp2fast(s[g][r] - m);
    float u8[8];
#pragma unroll
    for (int r = 0; r < 8; ++r) {
        float v = s[0][r] + s[0][r + 8];
#pragma unroll
        for (int g = 1; g < NG; ++g) v += s[g][r] + s[g][r + 8];
        u8[r] = v;
    }
#pragma unroll
    for (int r = 0; r < 4; ++r) u8[r] = u8[r] + u8[r + 4];
    float ps = (u8[0] + u8[1]) + (u8[2] + u8[3]);
    l += ps + __shfl_xor(ps, 32, 64);

    // pack + PV (round-4 verified shfl_xor routing, per 16-key fragment)
    __builtin_amdgcn_s_setprio(1);
#pragma unroll
    for (int cc = 0; cc < 2 * NG; ++cc) {
        const f32x16& ph = s[cc >> 1];  // constant index after unroll
        const int bse = (cc & 1) * 8;
        uint x0 = pkbf(ph[bse + 0], ph[bse + 1]);
        uint x1 = pkbf(ph[bse + 2], ph[bse + 3]);
        uint y0 = pkbf(ph[bse + 4], ph[bse + 5]);
        uint y1 = pkbf(ph[bse + 6], ph[bse + 7]);
        uint sx0 = __shfl_xor(x0, 32, 64), sx1 = __shfl_xor(x1, 32, 64);
        uint sy0 = __shfl_xor(y0, 32, 64), sy1 = __shfl_xor(y1, 32, 64);
        u32x4 wv;
        wv.x = hi ? sy0 : x0;
        wv.y = hi ? sy1 : x1;
        wv.z = hi ? y0 : sx0;
        wv.w = hi ? y1 : sx1;
        bf16x8 pa = __builtin_bit_cast(bf16x8, wv);
        o0 = MFMA32(pa, vfa[cc], o0);
        o1 = MFMA32(pa, vfb[cc], o1);
    }
    __builtin_amdgcn_s_setprio(0);
}

// Q-block 128 rows (4 waves x 32 q). 128-key K/V tiles shared by all waves,
// staged via global_load_lds into XOR-swizzled LDS (pre-swizzled global src),
// double-buffered with counted vmcnt + raw s_barrier.
__global__ __launch_bounds__(256) void attn_fwd(const bf16* __restrict__ Q,
                                                const bf16* __restrict__ K,
                                                const bf16* __restrict__ Vt,
                                                bf16* __restrict__ O) {
    __shared__ __align__(16) bf16 Kl[2][128 * 64];  // [key][d], swizzled
    __shared__ __align__(16) bf16 Vl[2][64 * 128];  // [d][key], swizzled

    const int g = blockIdx.x;
    const int lo = g & 255;
    const int xcd = lo & 7, jj = lo >> 3;       // jj 0..31
    const int hb = xcd * 4 + (jj & 3);          // 4 head-batches per XCD
    const int qhi = 15 - (jj >> 2);             // 8..15
    const int qb = (g < 256) ? qhi : 15 - qhi;  // heavy half first
    const int h = hb & 15, b = hb >> 4;

    const int tid = threadIdx.x, lane = tid & 63, w = tid >> 6;
    const int l31 = lane & 31, hi = lane >> 5;
    const int q0 = qb * 128 + w * 32;  // this wave's 32 q-rows

    const bf16* Qp = Q + (size_t)b * T * E + h * Dh;
    const bf16* Kp = K + (size_t)b * T * E + h * Dh;
    const bf16* Vp = Vt + ((size_t)b * E + h * Dh) * T;

    const int swz = (l31 & 7);  // read-side XOR

    bf16x8 qf[4];
#pragma unroll
    for (int t = 0; t < 4; ++t)
        qf[t] = *(const bf16x8*)(Qp + (size_t)(q0 + l31) * E + t * 16 + hi * 8);

    f32x16 o0 = {}, o1 = {};
    float m = -1e30f, l = 0.f;
    const int nK4 = qb + 1;  // 128-key tiles; last one is the diagonal tile

    // prologue: stage tile 0 into buf 0 (8 gll16 per wave: 4 K + 4 V)
    stageKV128(Kp, Vp, &Kl[0][0], &Vl[0][0], w, lane);

    int cur = 0;
#pragma unroll 1
    for (int K4 = 0; K4 < nK4; ++K4) {
        if (K4 + 1 < nK4) {
            stageKV128(Kp + (size_t)(K4 + 1) * 128 * E, Vp + (K4 + 1) * 128,
                       &Kl[cur ^ 1][0], &Vl[cur ^ 1][0], w, lane);
            asm volatile("s_waitcnt vmcnt(8)" ::: "memory");  // cur landed; next in flight
        } else {
            asm volatile("s_waitcnt vmcnt(0)" ::: "memory");
        }
        __builtin_amdgcn_s_barrier();
        asm volatile("" ::: "memory");

        const bf16* KL = &Kl[cur][0];
        const bf16* VL = &Vl[cur][0];
        if (K4 < qb) {
            attn_tile128<4, -1>(KL, VL, l31, hi, swz, qf, o0, o1, m, l);
        } else {  // diagonal 128-tile: wave w has w+1 live groups, group w masked
            if (w == 0)
                attn_tile128<1, 0>(KL, VL, l31, hi, swz, qf, o0, o1, m, l);
            else if (w == 1)
                attn_tile128<2, 1>(KL, VL, l31, hi, swz, qf, o0, o1, m, l);
            else if (w == 2)
                attn_tile128<3, 2>(KL, VL, l31, hi, swz, qf, o0, o1, m, l);
            else
                attn_tile128<4, 3>(KL, VL, l31, hi, swz, qf, o0, o1, m, l);
        }
        asm volatile("" ::: "memory");
        __builtin_amdgcn_s_barrier();  // all waves done reading buf[cur]
        cur ^= 1;
    }

    // epilogue: direct store (each wave owns its 32 q-rows)
    bf16* Op = O + (size_t)b * T * E + h * Dh;
#pragma unroll
    for (int r = 0; r < 16; ++r) {
        int qr = (r & 3) + 8 * (r >> 2) + 4 * hi;
        float lq = __shfl(l, qr, 64);
        float inv = 1.0f / lq;
        Op[(size_t)(q0 + qr) * E + l31] = (bf16)(o0[r] * inv);
        Op[(size_t)(q0 + qr) * E + 32 + l31] = (bf16)(o1[r] * inv);
    }
}

extern "C" void kernel_launch(void* const* d_in, const int* in_sizes, int n_in,
                              void* d_out, int out_size, void* d_ws, size_t ws_size,
                              hipStream_t stream) {
    const float* k_in = (const float*)d_in[0];
    const float* q_in = (const float*)d_in[1];
    const float* v_in = (const float*)d_in[2];
    const float* Wk = (const float*)d_in[3];
    const float* Wq = (const float*)d_in[4];
    const float* Wv = (const float*)d_in[5];
    const float* Wo = (const float*)d_in[6];
    const float* bo = (const float*)d_in[7];
    float* out = (float*)d_out;

    const size_t NE = (size_t)Bsz * T * E;  // 4M
    const size_t NW = (size_t)E * E;        // 1M
    bf16* ws = (bf16*)d_ws;
    bf16* Qb = ws;            // [B*T][E]  (pre-scaled by QSCALE)
    bf16* Kb = ws + NE;       // [B*T][E]
    bf16* Vt = ws + 2 * NE;   // [B][E][T]  (pre-transposed V)
    bf16* Ab = ws + 3 * NE;   // attn out; also aliases qc (dead by then)
    bf16* Wqc = ws + 4 * NE;
    bf16* Wkc = Wqc + NW;
    bf16* Wvc = Wkc + NW;
    bf16* Woc = Wvc + NW;
    bf16* qc = Ab;            // alias: qc dead after qkv_proj, Ab written after
    bf16* kc = ws + 4 * NE + 4 * NW;
    bf16* vc = kc + NE;

    const bool planA = ws_size >= (4 * NE + 4 * NW + 2 * NE) * sizeof(bf16);  // 56 MB
    const bool planB = ws_size >= (4 * NE + 4 * NW) * sizeof(bf16);           // 40 MB

    if (planA) {
        cvt_all<<<2048, 256, 0, stream>>>(q_in, k_in, v_in, Wq, Wk, Wv, Wo,
                                          qc, kc, vc, Wqc, Wkc, Wvc, Woc, 1);
        qkv_proj<true, true><<<768, 256, 0, stream>>>(
            nullptr, nullptr, nullptr, qc, kc, vc,
            nullptr, nullptr, nullptr, Wqc, Wkc, Wvc, Qb, Kb, Vt);
    } else if (planB) {
        cvt_all<<<2048, 256, 0, stream>>>(q_in, k_in, v_in, Wq, Wk, Wv, Wo,
                                          nullptr, nullptr, nullptr, Wqc, Wkc, Wvc, Woc, 0);
        qkv_proj<false, true><<<768, 256, 0, stream>>>(
            q_in, k_in, v_in, nullptr, nullptr, nullptr,
            nullptr, nullptr, nullptr, Wqc, Wkc, Wvc, Qb, Kb, Vt);
    } else {
        qkv_proj<false, false><<<768, 256, 0, stream>>>(
            q_in, k_in, v_in, nullptr, nullptr, nullptr,
            Wq, Wk, Wv, nullptr, nullptr, nullptr, Qb, Kb, Vt);
    }

    attn_fwd<<<dim3(512), 256, 0, stream>>>(Qb, Kb, Vt, Ab);

    if (planB)
        out_proj<true><<<512, 256, 0, stream>>>(Ab, Woc, nullptr, out, bo);
    else
        out_proj<false><<<512, 256, 0, stream>>>(Ab, nullptr, Wo, out, bo);
}

// Round 13
// 143.781 us; speedup vs baseline: 1.0790x; 1.0790x over previous
//
#include <hip/hip_runtime.h>
#include <stdint.h>

typedef __bf16 bf16;
typedef bf16 bf16x8 __attribute__((ext_vector_type(8)));
typedef bf16 bf16x4 __attribute__((ext_vector_type(4)));
typedef float f32x4 __attribute__((ext_vector_type(4)));
typedef float f32x16 __attribute__((ext_vector_type(16)));
typedef unsigned int uint;
typedef uint u32x4 __attribute__((ext_vector_type(4)));

#define MFMA16(a, b, c) __builtin_amdgcn_mfma_f32_16x16x32_bf16(a, b, c, 0, 0, 0)
#define MFMA32(a, b, c) __builtin_amdgcn_mfma_f32_32x32x16_bf16(a, b, c, 0, 0, 0)

static constexpr int Bsz = 2, T = 2048, E = 1024, H = 16, Dh = 64;
// softmax scale folded into Q at projection; exp2-domain: 1/sqrt(64) * log2(e)
static constexpr float QSCALE = 0.125f * 1.44269504088896f;

__device__ __forceinline__ float exp2fast(float x) {
#if __has_builtin(__builtin_amdgcn_exp2f)
    return __builtin_amdgcn_exp2f(x);
#else
    return exp2f(x);
#endif
}

// async global->LDS, 16B per lane. LDS dest must be wave-uniform base (HW adds lane*16).
__device__ __forceinline__ void gll16(const bf16* g, bf16* l) {
    __builtin_amdgcn_global_load_lds((const __attribute__((address_space(1))) uint*)g,
                                     (__attribute__((address_space(3))) uint*)l, 16, 0, 0);
}

// ---- staging: ROWS x 64 bf16 tile into linear LDS ([row][64], 128B rows) ----
template <int ROWS>
__device__ __forceinline__ void stage_b16(bf16* lds, const bf16* g, int ldg, int wave, int lane) {
#pragma unroll
    for (int i = 0; i < ROWS / 32; ++i) {
        const int row = wave * (ROWS / 4) + i * 8;  // wave-uniform
        gll16(g + (size_t)(row + (lane >> 3)) * ldg + (lane & 7) * 8, lds + row * 64);
    }
}
template <int ROWS>
__device__ __forceinline__ void stage_f32(bf16* lds, const float* g, int ldg, int tid) {
#pragma unroll
    for (int i = 0; i < ROWS / 16; ++i) {
        int gg = tid + i * 256;
        int row = gg >> 4, c4 = (gg & 15) << 2;
        const float4 v = *(const float4*)(g + (size_t)row * ldg + c4);
        bf16x4 bv = {(bf16)v.x, (bf16)v.y, (bf16)v.z, (bf16)v.w};
        *(bf16x4*)(lds + row * 64 + c4) = bv;
    }
}

// ------------- GEMM body: Y[M,N] = A[M,K] @ B[N,K]^T (+bias) ---------------
template <bool AB16, bool BB16, int MF, int NF, bool OUTF32>
__device__ __forceinline__ void gemm_body(bf16* At, bf16* Bt,
                                          const bf16* A16, const float* A32,
                                          const bf16* B16, const float* B32,
                                          bf16* Yb, float* Yf, const float* bias,
                                          int m0, int n0, int K, int ldy, float oscale) {
    constexpr int BM = MF * 32, BN = NF * 32;
    const int tid = threadIdx.x, lane = tid & 63, wave = tid >> 6;
    const int wm = wave >> 1, wn = wave & 1;
    const int fr = lane & 15, kg = (lane >> 4) << 3;

    f32x4 acc[MF][NF] = {};

    for (int k0 = 0; k0 < K; k0 += 64) {
        if constexpr (AB16)
            stage_b16<BM>(At, A16 + (size_t)m0 * K + k0, K, wave, lane);
        else
            stage_f32<BM>(At, A32 + (size_t)m0 * K + k0, K, tid);
        if constexpr (BB16)
            stage_b16<BN>(Bt, B16 + (size_t)n0 * K + k0, K, wave, lane);
        else
            stage_f32<BN>(Bt, B32 + (size_t)n0 * K + k0, K, tid);
        __syncthreads();  // compiler drains vmcnt(0) for global_load_lds here
#pragma unroll
        for (int kk = 0; kk < 64; kk += 32) {
            bf16x8 af[MF], bfr[NF];
#pragma unroll
            for (int f = 0; f < MF; ++f)
                af[f] = *(const bf16x8*)(At + (wm * (BM / 2) + f * 16 + fr) * 64 + kk + kg);
#pragma unroll
            for (int f = 0; f < NF; ++f)
                bfr[f] = *(const bf16x8*)(Bt + (wn * (BN / 2) + f * 16 + fr) * 64 + kk + kg);
#pragma unroll
            for (int mf = 0; mf < MF; ++mf)
#pragma unroll
                for (int nf = 0; nf < NF; ++nf)
                    acc[mf][nf] = MFMA16(af[mf], bfr[nf], acc[mf][nf]);
        }
        __syncthreads();
    }
    const int rb = (lane >> 4) << 2;
#pragma unroll
    for (int mf = 0; mf < MF; ++mf)
#pragma unroll
        for (int nf = 0; nf < NF; ++nf) {
            int n = n0 + wn * (BN / 2) + nf * 16 + fr;
            float bn = 0.f;
            if constexpr (OUTF32) bn = bias[n];
#pragma unroll
            for (int r = 0; r < 4; ++r) {
                int mm = m0 + wm * (BM / 2) + mf * 16 + rb + r;
                float v = acc[mf][nf][r];
                if constexpr (OUTF32)
                    Yf[(size_t)mm * ldy + n] = v + bn;
                else
                    Yb[(size_t)mm * ldy + n] = (bf16)(v * oscale);
            }
        }
}

// fp32 -> bf16 conversion pass (x inputs optional). 16M elems max, 4/thread.
__global__ __launch_bounds__(256) void cvt_all(const float* q, const float* k, const float* v,
                                               const float* Wq, const float* Wk,
                                               const float* Wv, const float* Wo,
                                               bf16* qc, bf16* kc, bf16* vc,
                                               bf16* Wqc, bf16* Wkc, bf16* Wvc, bf16* Woc,
                                               int doX) {
    const size_t NX = (size_t)Bsz * T * E;  // 4M
    const size_t NW = (size_t)E * E;        // 1M
    const size_t xtot = doX ? 3 * NX : 0;
    const size_t nwork = (xtot + 4 * NW) >> 2;
    for (size_t t = (size_t)blockIdx.x * 256 + threadIdx.x; t < nwork;
         t += (size_t)gridDim.x * 256) {
        size_t i = t << 2;
        const float* s;
        bf16* d;
        size_t off;
        if (i < xtot) {
            size_t w = i / NX;
            off = i - w * NX;
            s = w == 0 ? q : (w == 1 ? k : v);
            d = w == 0 ? qc : (w == 1 ? kc : vc);
        } else {
            size_t j = i - xtot;
            size_t w = j / NW;
            off = j - w * NW;
            s = w == 0 ? Wq : (w == 1 ? Wk : (w == 2 ? Wv : Wo));
            d = w == 0 ? Wqc : (w == 1 ? Wkc : (w == 2 ? Wvc : Woc));
        }
        const float4 x = *(const float4*)(s + off);
        bf16x4 y = {(bf16)x.x, (bf16)x.y, (bf16)x.z, (bf16)x.w};
        *(bf16x4*)(d + off) = y;
    }
}

// Fused Q/K/V^T projections: 768 blocks, XCD-swizzled, no dead blocks.
template <bool XB16, bool WB16>
__global__ __launch_bounds__(256) void qkv_proj(
    const float* q32, const float* k32, const float* v32,
    const bf16* q16, const bf16* k16, const bf16* v16,
    const float* Wq32, const float* Wk32, const float* Wv32,
    const bf16* Wq16, const bf16* Wk16, const bf16* Wv16,
    bf16* Qb, bf16* Kb, bf16* Vt) {
    __shared__ bf16 At[128 * 64];
    __shared__ bf16 Bt[128 * 64];
    const int bid = blockIdx.x;
    const int wid = (bid & 7) * 96 + (bid >> 3);  // 768 % 8 == 0: bijective
    if (wid < 512) {
        int s = wid >> 8;  // 0=Q (scaled by QSCALE), 1=K
        int t = wid & 255;
        int m0 = (t >> 3) * 128, n0 = (t & 7) * 128;
        gemm_body<XB16, WB16, 4, 4, false>(At, Bt,
                                           s ? k16 : q16, s ? k32 : q32,
                                           s ? Wk16 : Wq16, s ? Wk32 : Wq32,
                                           s ? Kb : Qb, nullptr, nullptr, m0, n0, E, E,
                                           s ? 1.0f : QSCALE);
    } else {
        int r = wid - 512;
        int b = r >> 7, rr = r & 127;
        int m0 = (rr >> 4) * 128, n0 = (rr & 15) * 128;
        gemm_body<WB16, XB16, 4, 4, false>(At, Bt,
                                           Wv16, Wv32,
                                           v16 + (size_t)b * T * E, v32 + (size_t)b * T * E,
                                           Vt + (size_t)b * E * T, nullptr, nullptr,
                                           m0, n0, E, T, 1.0f);
    }
}

// Output projection: 64x128 tiles -> 512 blocks (2/CU), fp32 out + bias.
template <bool WB16>
__global__ __launch_bounds__(256) void out_proj(const bf16* Xb, const bf16* W16,
                                                const float* W32, float* Y,
                                                const float* bias) {
    __shared__ bf16 At[64 * 64];
    __shared__ bf16 Bt[128 * 64];
    const int bid = blockIdx.x;
    const int wid = (bid & 7) * 64 + (bid >> 3);  // 512 % 8 == 0: bijective
    const int m0 = (wid >> 3) * 64, n0 = (wid & 7) * 128;
    gemm_body<true, WB16, 2, 4, true>(At, Bt, Xb, nullptr, W16, W32, nullptr, Y, bias,
                                      m0, n0, E, E, 1.0f);
}

// ---------------- Attention: flash, shared LDS-staged K/V tiles ------------
__device__ __forceinline__ uint pkbf(float a, float b) {
    uint16_t x = __builtin_bit_cast(uint16_t, (bf16)a);
    uint16_t y = __builtin_bit_cast(uint16_t, (bf16)b);
    return (uint)x | ((uint)y << 16);
}

// One flat 64-key tile. DMODE: 0 = interior (no mask), 1 = diagonal with q in
// upper half (s1 diag-masked), 2 = diagonal with q in lower half (s0
// diag-masked, keys 32-63 entirely dead -> skipped).
// Two independent QK chains (s0,s1); ONE softmax pass over all 32 scores.
template <int DMODE>
__device__ __forceinline__ void attn_tile64(const bf16* KL, const bf16* VL,
                                            int l31, int hi, int swz,
                                            const bf16x8 (&qf)[4],
                                            f32x16& o0, f32x16& o1, float& m, float& l) {
    constexpr int NCC = (DMODE == 2) ? 2 : 4;
    f32x16 s0 = {}, s1 = {};
    {
        bf16x8 kf[4];
#pragma unroll
        for (int t = 0; t < 4; ++t)
            kf[t] = *(const bf16x8*)(KL + l31 * 64 + ((((t << 1) | hi) ^ swz) << 3));
        __builtin_amdgcn_s_setprio(1);
#pragma unroll
        for (int t = 0; t < 4; ++t) s0 = MFMA32(kf[t], qf[t], s0);
        __builtin_amdgcn_s_setprio(0);
    }
    if constexpr (DMODE != 2) {
        bf16x8 kf[4];
#pragma unroll
        for (int t = 0; t < 4; ++t)
            kf[t] = *(const bf16x8*)(KL + (32 + l31) * 64 + ((((t << 1) | hi) ^ swz) << 3));
        __builtin_amdgcn_s_setprio(1);
#pragma unroll
        for (int t = 0; t < 4; ++t) s1 = MFMA32(kf[t], qf[t], s1);
        __builtin_amdgcn_s_setprio(0);
    }
    // V fragments preloaded here: ds_read latency hides under softmax VALU
    bf16x8 vfa[NCC], vfb[NCC];
#pragma unroll
    for (int cc = 0; cc < NCC; ++cc) {
        vfa[cc] = *(const bf16x8*)(VL + l31 * 64 + ((((cc << 1) | hi) ^ swz) << 3));
        vfb[cc] = *(const bf16x8*)(VL + (32 + l31) * 64 + ((((cc << 1) | hi) ^ swz) << 3));
    }
    // causal mask (diagonal tiles only)
    if constexpr (DMODE == 2) {
#pragma unroll
        for (int r = 0; r < 16; ++r) {
            int key = (r & 3) + 8 * (r >> 2) + 4 * hi;
            if (key > l31) s0[r] = -1e30f;
        }
    }
    if constexpr (DMODE == 1) {
#pragma unroll
        for (int r = 0; r < 16; ++r) {
            int key = (r & 3) + 8 * (r >> 2) + 4 * hi;
            if (key > l31) s1[r] = -1e30f;
        }
    }
    // single row-max tree over all live scores
    float t8[8];
    if constexpr (DMODE == 2) {
#pragma unroll
        for (int r = 0; r < 8; ++r) t8[r] = fmaxf(s0[r], s0[r + 8]);
    } else {
#pragma unroll
        for (int r = 0; r < 8; ++r)
            t8[r] = fmaxf(fmaxf(s0[r], s0[r + 8]), fmaxf(s1[r], s1[r + 8]));
    }
#pragma unroll
    for (int r = 0; r < 4; ++r) t8[r] = fmaxf(t8[r], t8[r + 4]);
    float pm = fmaxf(fmaxf(t8[0], t8[1]), fmaxf(t8[2], t8[3]));
    pm = fmaxf(pm, __shfl_xor(pm, 32, 64));

    if (!__all(pm - m <= 11.5f)) {  // deferred rescale (T13), 8*log2e
        float mn = fmaxf(m, pm);
        float al = exp2fast(m - mn);
        m = mn;
        l *= al;
#pragma unroll
        for (int r = 0; r < 16; ++r) {
            int qr = (r & 3) + 8 * (r >> 2) + 4 * hi;
            float aq = __shfl(al, qr, 64);
            o0[r] *= aq;
            o1[r] *= aq;
        }
    }
    // exp in place (masked entries -> 0), single sum tree
#pragma unroll
    for (int r = 0; r < 16; ++r) s0[r] = exp2fast(s0[r] - m);
    if constexpr (DMODE != 2) {
#pragma unroll
        for (int r = 0; r < 16; ++r) s1[r] = exp2fast(s1[r] - m);
    }
    float u8[8];
    if constexpr (DMODE == 2) {
#pragma unroll
        for (int r = 0; r < 8; ++r) u8[r] = s0[r] + s0[r + 8];
    } else {
#pragma unroll
        for (int r = 0; r < 8; ++r) u8[r] = (s0[r] + s0[r + 8]) + (s1[r] + s1[r + 8]);
    }
#pragma unroll
    for (int r = 0; r < 4; ++r) u8[r] = u8[r] + u8[r + 4];
    float ps = (u8[0] + u8[1]) + (u8[2] + u8[3]);
    l += ps + __shfl_xor(ps, 32, 64);

    // pack + PV (round-4 verified shfl_xor routing, per 16-key fragment)
    __builtin_amdgcn_s_setprio(1);
#pragma unroll
    for (int cc = 0; cc < NCC; ++cc) {
        const f32x16& ph = (cc < 2) ? s0 : s1;  // static after unroll
        const int bse = (cc & 1) * 8;
        uint x0 = pkbf(ph[bse + 0], ph[bse + 1]);
        uint x1 = pkbf(ph[bse + 2], ph[bse + 3]);
        uint y0 = pkbf(ph[bse + 4], ph[bse + 5]);
        uint y1 = pkbf(ph[bse + 6], ph[bse + 7]);
        uint sx0 = __shfl_xor(x0, 32, 64), sx1 = __shfl_xor(x1, 32, 64);
        uint sy0 = __shfl_xor(y0, 32, 64), sy1 = __shfl_xor(y1, 32, 64);
        u32x4 wv;
        wv.x = hi ? sy0 : x0;
        wv.y = hi ? sy1 : x1;
        wv.z = hi ? y0 : sx0;
        wv.w = hi ? y1 : sx1;
        bf16x8 pa = __builtin_bit_cast(bf16x8, wv);
        o0 = MFMA32(pa, vfa[cc], o0);
        o1 = MFMA32(pa, vfb[cc], o1);
    }
    __builtin_amdgcn_s_setprio(0);
}

// Q-block 128 rows (4 waves x 32 q). 64-key K/V tiles shared by all waves,
// staged via global_load_lds into XOR-swizzled LDS (pre-swizzled global src),
// double-buffered with counted vmcnt + raw s_barrier.
__global__ __launch_bounds__(256) void attn_fwd(const bf16* __restrict__ Q,
                                                const bf16* __restrict__ K,
                                                const bf16* __restrict__ Vt,
                                                bf16* __restrict__ O) {
    __shared__ __align__(16) bf16 Kl[2][64 * 64];  // [key][d], 128B rows, swizzled
    __shared__ __align__(16) bf16 Vl[2][64 * 64];  // [d][key], 128B rows, swizzled

    const int g = blockIdx.x;
    const int lo = g & 255;
    const int xcd = lo & 7, jj = lo >> 3;       // jj 0..31
    const int hb = xcd * 4 + (jj & 3);          // 4 head-batches per XCD
    const int qhi = 15 - (jj >> 2);             // 8..15
    const int qb = (g < 256) ? qhi : 15 - qhi;  // heavy half first
    const int h = hb & 15, b = hb >> 4;

    const int tid = threadIdx.x, lane = tid & 63, w = tid >> 6;
    const int l31 = lane & 31, hi = lane >> 5;
    const int q0 = qb * 128 + w * 32;  // this wave's 32 q-rows

    const bf16* Qp = Q + (size_t)b * T * E + h * Dh;
    const bf16* Kp = K + (size_t)b * T * E + h * Dh;
    const bf16* Vp = Vt + ((size_t)b * E + h * Dh) * T;

    // staging lane geometry: linear LDS dest + pre-swizzled global source
    const int rsub = lane >> 3;         // row within 8-row slab
    const int csw = (lane & 7) ^ rsub;  // swizzled 16B-chunk index
    const int swz = (l31 & 7);          // read-side XOR

    bf16x8 qf[4];
#pragma unroll
    for (int t = 0; t < 4; ++t)
        qf[t] = *(const bf16x8*)(Qp + (size_t)(q0 + l31) * E + t * 16 + hi * 8);

    f32x16 o0 = {}, o1 = {};
    float m = -1e30f, l = 0.f;
    const int ktD = 2 * qb + (w >> 1);  // this wave's diagonal 64-tile
    const int nK2 = 2 * qb + 2;         // 64-key tiles staged by the block

    // prologue: stage tile 0 into buf 0 (4 gll16 per wave: 2 K + 2 V slabs)
#pragma unroll
    for (int ii = 0; ii < 2; ++ii)
        gll16(Kp + (size_t)(16 * w + 8 * ii + rsub) * E + csw * 8, &Kl[0][(2 * w + ii) * 512]);
#pragma unroll
    for (int ii = 0; ii < 2; ++ii)
        gll16(Vp + (size_t)(16 * w + 8 * ii + rsub) * T + csw * 8, &Vl[0][(2 * w + ii) * 512]);

    int cur = 0;
#pragma unroll 1
    for (int K2 = 0; K2 < nK2; ++K2) {
        if (K2 + 1 < nK2) {
            const int kb = (K2 + 1) * 64;
            const bf16* Kg = Kp + (size_t)kb * E;
            const bf16* Vg = Vp + kb;
            bf16* dK = &Kl[cur ^ 1][0];
            bf16* dV = &Vl[cur ^ 1][0];
#pragma unroll
            for (int ii = 0; ii < 2; ++ii)
                gll16(Kg + (size_t)(16 * w + 8 * ii + rsub) * E + csw * 8, dK + (2 * w + ii) * 512);
#pragma unroll
            for (int ii = 0; ii < 2; ++ii)
                gll16(Vg + (size_t)(16 * w + 8 * ii + rsub) * T + csw * 8, dV + (2 * w + ii) * 512);
            asm volatile("s_waitcnt vmcnt(4)" ::: "memory");  // cur-tile landed; next in flight
        } else {
            asm volatile("s_waitcnt vmcnt(0)" ::: "memory");
        }
        __builtin_amdgcn_s_barrier();
        asm volatile("" ::: "memory");

        const bf16* KL = &Kl[cur][0];
        const bf16* VL = &Vl[cur][0];
        if (K2 < ktD) {
            attn_tile64<0>(KL, VL, l31, hi, swz, qf, o0, o1, m, l);
        } else if (K2 == ktD) {
            if (w & 1)
                attn_tile64<1>(KL, VL, l31, hi, swz, qf, o0, o1, m, l);
            else
                attn_tile64<2>(KL, VL, l31, hi, swz, qf, o0, o1, m, l);
        }
        asm volatile("" ::: "memory");
        __builtin_amdgcn_s_barrier();  // all waves done reading buf[cur]
        cur ^= 1;
    }

    // epilogue: direct store (each wave owns its 32 q-rows)
    bf16* Op = O + (size_t)b * T * E + h * Dh;
#pragma unroll
    for (int r = 0; r < 16; ++r) {
        int qr = (r & 3) + 8 * (r >> 2) + 4 * hi;
        float lq = __shfl(l, qr, 64);
        float inv = 1.0f / lq;
        Op[(size_t)(q0 + qr) * E + l31] = (bf16)(o0[r] * inv);
        Op[(size_t)(q0 + qr) * E + 32 + l31] = (bf16)(o1[r] * inv);
    }
}

extern "C" void kernel_launch(void* const* d_in, const int* in_sizes, int n_in,
                              void* d_out, int out_size, void* d_ws, size_t ws_size,
                              hipStream_t stream) {
    const float* k_in = (const float*)d_in[0];
    const float* q_in = (const float*)d_in[1];
    const float* v_in = (const float*)d_in[2];
    const float* Wk = (const float*)d_in[3];
    const float* Wq = (const float*)d_in[4];
    const float* Wv = (const float*)d_in[5];
    const float* Wo = (const float*)d_in[6];
    const float* bo = (const float*)d_in[7];
    float* out = (float*)d_out;

    const size_t NE = (size_t)Bsz * T * E;  // 4M
    const size_t NW = (size_t)E * E;        // 1M
    bf16* ws = (bf16*)d_ws;
    bf16* Qb = ws;            // [B*T][E]  (pre-scaled by QSCALE)
    bf16* Kb = ws + NE;       // [B*T][E]
    bf16* Vt = ws + 2 * NE;   // [B][E][T]  (pre-transposed V)
    bf16* Ab = ws + 3 * NE;   // attn out; also aliases qc (dead by then)
    bf16* Wqc = ws + 4 * NE;
    bf16* Wkc = Wqc + NW;
    bf16* Wvc = Wkc + NW;
    bf16* Woc = Wvc + NW;
    bf16* qc = Ab;            // alias: qc dead after qkv_proj, Ab written after
    bf16* kc = ws + 4 * NE + 4 * NW;
    bf16* vc = kc + NE;

    const bool planA = ws_size >= (4 * NE + 4 * NW + 2 * NE) * sizeof(bf16);  // 56 MB
    const bool planB = ws_size >= (4 * NE + 4 * NW) * sizeof(bf16);           // 40 MB

    if (planA) {
        cvt_all<<<2048, 256, 0, stream>>>(q_in, k_in, v_in, Wq, Wk, Wv, Wo,
                                          qc, kc, vc, Wqc, Wkc, Wvc, Woc, 1);
        qkv_proj<true, true><<<768, 256, 0, stream>>>(
            nullptr, nullptr, nullptr, qc, kc, vc,
            nullptr, nullptr, nullptr, Wqc, Wkc, Wvc, Qb, Kb, Vt);
    } else if (planB) {
        cvt_all<<<2048, 256, 0, stream>>>(q_in, k_in, v_in, Wq, Wk, Wv, Wo,
                                          nullptr, nullptr, nullptr, Wqc, Wkc, Wvc, Woc, 0);
        qkv_proj<false, true><<<768, 256, 0, stream>>>(
            q_in, k_in, v_in, nullptr, nullptr, nullptr,
            nullptr, nullptr, nullptr, Wqc, Wkc, Wvc, Qb, Kb, Vt);
    } else {
        qkv_proj<false, false><<<768, 256, 0, stream>>>(
            q_in, k_in, v_in, nullptr, nullptr, nullptr,
            Wq, Wk, Wv, nullptr, nullptr, nullptr, Qb, Kb, Vt);
    }

    attn_fwd<<<dim3(512), 256, 0, stream>>>(Qb, Kb, Vt, Ab);

    if (planB)
        out_proj<true><<<512, 256, 0, stream>>>(Ab, Woc, nullptr, out, bo);
    else
        out_proj<false><<<512, 256, 0, stream>>>(Ab, nullptr, Wo, out, bo);
}